// Round 10
// baseline (1406.459 us; speedup 1.0000x reference)
//
#include <hip/hip_runtime.h>
#include <hip/hip_cooperative_groups.h>
#include <math.h>

#define HID 64
#define HEADS 4
#define HDIM 16
#define N_MOL 2048
#define N_PROT 4096
#define E_MOL 32768
#define E_PROT 131072
#define BATCH 32
#define N_TOT (N_MOL + N_PROT)
#define E_TOT (E_MOL + E_PROT)
#define CAP 128        // bucket capacity per node (mean deg 16/32; overflow prob ~0)

// attention tiling (r8 proven config: 111us standalone)
#define TQA 16         // queries per block
#define TKA 32         // keys per LDS tile
#define KSTA 68        // LDS row stride (words)
#define CH_MOL 4       // key chunks for mol queries (1024 keys each)
#define CH_PROT 2      // key chunks for prot queries (1024 keys each)
#define KCHUNK 1024
#define NGRP_MOL (N_MOL / TQA)          // 128
#define ATTN_VB (NGRP_MOL * CH_MOL + (N_PROT / TQA) * CH_PROT)   // 1024

#define DOT4(a, b) ((a).x*(b).x + (a).y*(b).y + (a).z*(b).z + (a).w*(b).w)
#define EXP2(x) __builtin_amdgcn_exp2f(x)

struct Prm {
    const float *mol_x, *prot_x, *mol_ea, *prot_ea;
    const int *mol_ei, *prot_ei, *mol_b, *prot_b;
    const float *nlmW, *nlmb, *nlpW, *nlpb, *elmW, *elmb, *elpW, *elpb;
    const float *mcW1, *mcb1, *mcW2, *mcb2, *pcW1, *pcb1, *pcW2, *pcb2;
    const float *mpW, *mpb, *pmW, *pmb, *fc1W, *fc1b, *fc2W, *fc2b;
    float *xa_m, *xa_p, *xb_m, *xb_p, *Qm, *Kp, *Vp, *Qp, *Km, *Vm, *partm, *partp;
    int *cursor, *eidx;
    float* out;
};

union SMem {
    struct { float Kl[2][TKA * KSTA]; float Vl[2][TKA * KSTA]; } attn;  // 34816 B
    struct { float h0[8][HID]; float h1[8][HID]; } gine;                // 4096 B
    struct { float row[8][HID]; } qkv;                                  // 2048 B
    struct { float red[64][65]; float z[2 * HID]; } fin;                // 17152 B
};

__device__ inline void upd4(float4& A, const float4 v0, const float4 v1,
                            float p0, float p1, float al) {
    A.x = fmaf(p1, v1.x, fmaf(p0, v0.x, A.x * al));
    A.y = fmaf(p1, v1.y, fmaf(p0, v0.y, A.y * al));
    A.z = fmaf(p1, v1.z, fmaf(p0, v0.z, A.z * al));
    A.w = fmaf(p1, v1.w, fmaf(p0, v0.w, A.w * al));
}
__device__ inline void merge4(float4& A, const float4 B, float c1, float c2) {
    A.x = A.x * c1 + B.x * c2;
    A.y = A.y * c1 + B.y * c2;
    A.z = A.z * c1 + B.z * c2;
    A.w = A.w * c1 + B.w * c2;
}
__device__ inline float4 shfl4(const float4 a, int off) {
    float4 r;
    r.x = __shfl_xor(a.x, off, 64); r.y = __shfl_xor(a.y, off, 64);
    r.z = __shfl_xor(a.z, off, 64); r.w = __shfl_xor(a.w, off, 64);
    return r;
}

// ---------------------------------------------------------------------------
// GINE layer body (r8-proven): bucket gather + node MLP, 8 nodes/virtual-block,
// 2 per wave. Per-wave LDS slices -> no block barriers.
__device__ __forceinline__ void gine_layer(
    int vb, const float* xin_m, const float* xin_p, float* xout_m, float* xout_p,
    const Prm& p, const float* Wem, const float* bem, const float* Wep, const float* bep,
    const float* W1m, const float* b1m, const float* W2m, const float* b2m,
    const float* W1p, const float* b1p, const float* W2p, const float* b2p,
    float (*h0)[HID], float (*h1)[HID]) {
    int w = threadIdx.x >> 6, t = threadIdx.x & 63;
    int nb0 = vb * 8 + w * 2;
    bool isMol = nb0 < N_MOL;
    const float* x  = isMol ? xin_m : xin_p;
    float* xo       = isMol ? xout_m : xout_p;
    const float* We = isMol ? Wem : Wep;
    float bt        = isMol ? bem[t] : bep[t];
    const float* ea_base = isMol ? p.mol_ea : p.prot_ea;
    const int* srcarr    = isMol ? p.mol_ei : p.prot_ei;
    int nbias = isMol ? 0 : N_MOL;
    float wcol[10];
#pragma unroll
    for (int i = 0; i < 10; ++i) wcol[i] = We[i * HID + t];

#pragma unroll
    for (int u = 0; u < 2; ++u) {
        int nbx = nb0 + u;
        int deg = p.cursor[nbx];
        const int* lst = p.eidx + (size_t)nbx * CAP;
        float agg = 0.f;
        int j = 0;
        for (; j + 1 < deg; j += 2) {
            int e0 = lst[j], e1 = lst[j + 1];
            int s0 = srcarr[e0], s1 = srcarr[e1];
            const float2* q0 = (const float2*)(ea_base + (size_t)e0 * 10);
            const float2* q1 = (const float2*)(ea_base + (size_t)e1 * 10);
            float2 a0 = q0[0], a1 = q0[1], a2 = q0[2], a3 = q0[3], a4 = q0[4];
            float2 c0 = q1[0], c1 = q1[1], c2 = q1[2], c3 = q1[3], c4 = q1[4];
            float xs0 = x[s0 * HID + t];
            float xs1 = x[s1 * HID + t];
            float m0 = bt, m1 = bt;
            m0 = fmaf(a0.x, wcol[0], m0); m0 = fmaf(a0.y, wcol[1], m0);
            m0 = fmaf(a1.x, wcol[2], m0); m0 = fmaf(a1.y, wcol[3], m0);
            m0 = fmaf(a2.x, wcol[4], m0); m0 = fmaf(a2.y, wcol[5], m0);
            m0 = fmaf(a3.x, wcol[6], m0); m0 = fmaf(a3.y, wcol[7], m0);
            m0 = fmaf(a4.x, wcol[8], m0); m0 = fmaf(a4.y, wcol[9], m0);
            m1 = fmaf(c0.x, wcol[0], m1); m1 = fmaf(c0.y, wcol[1], m1);
            m1 = fmaf(c1.x, wcol[2], m1); m1 = fmaf(c1.y, wcol[3], m1);
            m1 = fmaf(c2.x, wcol[4], m1); m1 = fmaf(c2.y, wcol[5], m1);
            m1 = fmaf(c3.x, wcol[6], m1); m1 = fmaf(c3.y, wcol[7], m1);
            m1 = fmaf(c4.x, wcol[8], m1); m1 = fmaf(c4.y, wcol[9], m1);
            agg += fmaxf(m0 + xs0, 0.f) + fmaxf(m1 + xs1, 0.f);
        }
        if (j < deg) {
            int e0 = lst[j];
            int s0 = srcarr[e0];
            const float2* q0 = (const float2*)(ea_base + (size_t)e0 * 10);
            float2 a0 = q0[0], a1 = q0[1], a2 = q0[2], a3 = q0[3], a4 = q0[4];
            float xs0 = x[s0 * HID + t];
            float m0 = bt;
            m0 = fmaf(a0.x, wcol[0], m0); m0 = fmaf(a0.y, wcol[1], m0);
            m0 = fmaf(a1.x, wcol[2], m0); m0 = fmaf(a1.y, wcol[3], m0);
            m0 = fmaf(a2.x, wcol[4], m0); m0 = fmaf(a2.y, wcol[5], m0);
            m0 = fmaf(a3.x, wcol[6], m0); m0 = fmaf(a3.y, wcol[7], m0);
            m0 = fmaf(a4.x, wcol[8], m0); m0 = fmaf(a4.y, wcol[9], m0);
            agg += fmaxf(m0 + xs0, 0.f);
        }
        h0[w * 2 + u][t] = x[(nb0 - nbias + u) * HID + t] + agg;
    }

    const float* W1 = isMol ? W1m : W1p;
    const float* W2 = isMol ? W2m : W2p;
    float b1v = isMol ? b1m[t] : b1p[t];
    float b2v = isMol ? b2m[t] : b2p[t];
    float acc0 = b1v, acc1 = b1v;
    const float4* hA = (const float4*)h0[w * 2];
    const float4* hB = (const float4*)h0[w * 2 + 1];
#pragma unroll
    for (int k = 0; k < 16; ++k) {
        float4 a = hA[k], b = hB[k];
        float w0 = W1[(4 * k + 0) * HID + t], w1 = W1[(4 * k + 1) * HID + t];
        float w2 = W1[(4 * k + 2) * HID + t], w3 = W1[(4 * k + 3) * HID + t];
        acc0 = fmaf(a.x, w0, acc0); acc1 = fmaf(b.x, w0, acc1);
        acc0 = fmaf(a.y, w1, acc0); acc1 = fmaf(b.y, w1, acc1);
        acc0 = fmaf(a.z, w2, acc0); acc1 = fmaf(b.z, w2, acc1);
        acc0 = fmaf(a.w, w3, acc0); acc1 = fmaf(b.w, w3, acc1);
    }
    h1[w * 2][t] = fmaxf(acc0, 0.f);
    h1[w * 2 + 1][t] = fmaxf(acc1, 0.f);
    float d0 = b2v, d1 = b2v;
    const float4* gA = (const float4*)h1[w * 2];
    const float4* gB = (const float4*)h1[w * 2 + 1];
#pragma unroll
    for (int k = 0; k < 16; ++k) {
        float4 a = gA[k], b = gB[k];
        float w0 = W2[(4 * k + 0) * HID + t], w1 = W2[(4 * k + 1) * HID + t];
        float w2 = W2[(4 * k + 2) * HID + t], w3 = W2[(4 * k + 3) * HID + t];
        d0 = fmaf(a.x, w0, d0); d1 = fmaf(b.x, w0, d1);
        d0 = fmaf(a.y, w1, d0); d1 = fmaf(b.y, w1, d1);
        d0 = fmaf(a.z, w2, d0); d1 = fmaf(b.z, w2, d1);
        d0 = fmaf(a.w, w3, d0); d1 = fmaf(b.w, w3, d1);
    }
    int n0 = nb0 - nbias;
    xo[n0 * HID + t] = fmaxf(d0, 0.f);
    xo[(n0 + 1) * HID + t] = fmaxf(d1, 0.f);
}

// ---------------------------------------------------------------------------
// One cooperative launch for the whole network. Phases separated by
// grid.sync() (collective barrier = cheap device-wide fence; NOT the r7
// per-block __threadfence pattern). All phases grid-stride over virtual
// blocks so any co-resident grid size works.
__global__ __launch_bounds__(256, 4) void k_mega(Prm p) {
    cooperative_groups::grid_group gg = cooperative_groups::this_grid();
    __shared__ SMem smem;
    const int t = threadIdx.x;
    const int nb = gridDim.x;

    // ---- phase Z: zero bucket cursors
    for (int i = blockIdx.x * 256 + t; i < N_TOT; i += nb * 256) p.cursor[i] = 0;
    gg.sync();

    // ---- phase A: node linear (1536 vb) + edge bucketing (640 vb)
    for (int vb = blockIdx.x; vb < N_TOT / 4 + E_TOT / 256; vb += nb) {
        if (vb < N_TOT / 4) {
            int w = t >> 6, l = t & 63;
            int n = vb * 4 + w;
            if (n < N_MOL) {
                const float* xr = p.mol_x + n * 11;
                float acc = p.nlmb[l];
#pragma unroll
                for (int i = 0; i < 11; ++i) acc += xr[i] * p.nlmW[i * HID + l];
                p.xa_m[n * HID + l] = acc;
            } else {
                int q = n - N_MOL;
                const float* xr = p.prot_x + q * 15;
                float acc = p.nlpb[l];
#pragma unroll
                for (int i = 0; i < 15; ++i) acc += xr[i] * p.nlpW[i * HID + l];
                p.xa_p[q * HID + l] = acc;
            }
        } else {
            int e = (vb - N_TOT / 4) * 256 + t;
            int node, loc;
            if (e < E_MOL) { node = p.mol_ei[E_MOL + e]; loc = e; }
            else { int el = e - E_MOL; node = N_MOL + p.prot_ei[E_PROT + el]; loc = el; }
            int pos = atomicAdd(&p.cursor[node], 1);
            p.eidx[(size_t)node * CAP + pos] = loc;
        }
    }
    gg.sync();

    // ---- phases B/C/D: 3 GINE layers, ping-pong xa <-> xb (result in xb)
    for (int vb = blockIdx.x; vb < N_TOT / 8; vb += nb)
        gine_layer(vb, p.xa_m, p.xa_p, p.xb_m, p.xb_p, p,
                   p.elmW, p.elmb, p.elpW, p.elpb,
                   p.mcW1, p.mcb1, p.mcW2, p.mcb2,
                   p.pcW1, p.pcb1, p.pcW2, p.pcb2, smem.gine.h0, smem.gine.h1);
    gg.sync();
    for (int vb = blockIdx.x; vb < N_TOT / 8; vb += nb)
        gine_layer(vb, p.xb_m, p.xb_p, p.xa_m, p.xa_p, p,
                   p.elmW, p.elmb, p.elpW, p.elpb,
                   p.mcW1 + 4096, p.mcb1 + 64, p.mcW2 + 4096, p.mcb2 + 64,
                   p.pcW1 + 4096, p.pcb1 + 64, p.pcW2 + 4096, p.pcb2 + 64,
                   smem.gine.h0, smem.gine.h1);
    gg.sync();
    for (int vb = blockIdx.x; vb < N_TOT / 8; vb += nb)
        gine_layer(vb, p.xa_m, p.xa_p, p.xb_m, p.xb_p, p,
                   p.elmW, p.elmb, p.elpW, p.elpb,
                   p.mcW1 + 8192, p.mcb1 + 128, p.mcW2 + 8192, p.mcb2 + 128,
                   p.pcW1 + 8192, p.pcb1 + 128, p.pcW2 + 8192, p.pcb2 + 128,
                   smem.gine.h0, smem.gine.h1);
    gg.sync();

    // ---- phase E: QKV projections (2304 vb, 8 rows each, 2 per wave)
    for (int vb = blockIdx.x; vb < 18432 / 8; vb += nb) {
        int w = t >> 6, l = t & 63;
        int b0 = vb * 8;
        const float *src, *W, *bias;
        float* dst;
        int base;
        if (b0 < 2048)       { base = 0;     src = p.xb_m; W = p.mpW;        bias = p.mpb;       dst = p.Qm; }
        else if (b0 < 6144)  { base = 2048;  src = p.xb_p; W = p.mpW + 4096; bias = p.mpb + 64;  dst = p.Kp; }
        else if (b0 < 10240) { base = 6144;  src = p.xb_p; W = p.mpW + 8192; bias = p.mpb + 128; dst = p.Vp; }
        else if (b0 < 14336) { base = 10240; src = p.xb_p; W = p.pmW;        bias = p.pmb;       dst = p.Qp; }
        else if (b0 < 16384) { base = 14336; src = p.xb_m; W = p.pmW + 4096; bias = p.pmb + 64;  dst = p.Km; }
        else                 { base = 16384; src = p.xb_m; W = p.pmW + 8192; bias = p.pmb + 128; dst = p.Vm; }
        int n0 = b0 - base + w * 2, n1 = n0 + 1;
        smem.qkv.row[w * 2][l] = src[n0 * HID + l];
        smem.qkv.row[w * 2 + 1][l] = src[n1 * HID + l];
        float acc0 = bias[l], acc1 = acc0;
        const float4* rA = (const float4*)smem.qkv.row[w * 2];
        const float4* rB = (const float4*)smem.qkv.row[w * 2 + 1];
#pragma unroll
        for (int k = 0; k < 16; ++k) {
            float4 a = rA[k], b = rB[k];
            float w0 = W[(4 * k + 0) * HID + l], w1 = W[(4 * k + 1) * HID + l];
            float w2 = W[(4 * k + 2) * HID + l], w3 = W[(4 * k + 3) * HID + l];
            acc0 = fmaf(a.x, w0, acc0); acc1 = fmaf(b.x, w0, acc1);
            acc0 = fmaf(a.y, w1, acc0); acc1 = fmaf(b.y, w1, acc1);
            acc0 = fmaf(a.z, w2, acc0); acc1 = fmaf(b.z, w2, acc1);
            acc0 = fmaf(a.w, w3, acc0); acc1 = fmaf(b.w, w3, acc1);
        }
        dst[n0 * HID + l] = acc0;
        dst[n1 * HID + l] = acc1;
    }
    gg.sync();

    // ---- phase F: tiled cross attention (1024 vb; r8 structure, 111us proven)
    for (int vb0 = blockIdx.x; vb0 < ATTN_VB; vb0 += nb) {
        const float *Q, *K, *V;
        float* part;
        int q0, chunk, CH;
        {
            int b = vb0;
            const int MOLB = NGRP_MOL * CH_MOL;   // 512
            if (b < MOLB) {
                chunk = b & 3; q0 = (b >> 2) * TQA; CH = CH_MOL;
                Q = p.Qm; K = p.Kp; V = p.Vp; part = p.partm;
            } else {
                b -= MOLB;
                chunk = b & 1; q0 = (b >> 1) * TQA; CH = CH_PROT;
                Q = p.Qp; K = p.Km; V = p.Vm; part = p.partp;
            }
        }
        int kbeg = chunk * KCHUNK;

        int sub = t & 15, h = (t >> 4) & 3, qg = t >> 6;
        int r0 = t >> 4, c0 = (t & 15) << 2;

        const float sc = 0.25f * 1.44269504088896f;   // 1/sqrt(16) * log2(e)
        float4 q4[4][4];
#pragma unroll
        for (int qq = 0; qq < 4; ++qq) {
            const float4* Qr = (const float4*)(Q + (q0 + qg * 4 + qq) * HID + h * HDIM);
#pragma unroll
            for (int j = 0; j < 4; ++j) {
                float4 v = Qr[j];
                v.x *= sc; v.y *= sc; v.z *= sc; v.w *= sc;
                q4[qq][j] = v;
            }
        }

        float mreg[4], lreg[4];
        float4 A[4][4];
#pragma unroll
        for (int qq = 0; qq < 4; ++qq) {
            mreg[qq] = -INFINITY; lreg[qq] = 0.f;
#pragma unroll
            for (int j = 0; j < 4; ++j) A[qq][j] = (float4){0.f, 0.f, 0.f, 0.f};
        }

        __syncthreads();   // protect LDS reuse across vb iterations / phases
        {
            const float4* Kg = (const float4*)(K + kbeg * HID);
            const float4* Vg = (const float4*)(V + kbeg * HID);
            float4 ka = Kg[t], kb = Kg[t + 256];
            float4 va = Vg[t], vb = Vg[t + 256];
            *(float4*)&smem.attn.Kl[0][r0 * KSTA + c0] = ka;
            *(float4*)&smem.attn.Kl[0][(r0 + 16) * KSTA + c0] = kb;
            *(float4*)&smem.attn.Vl[0][r0 * KSTA + c0] = va;
            *(float4*)&smem.attn.Vl[0][(r0 + 16) * KSTA + c0] = vb;
        }
        __syncthreads();

        const int NT = KCHUNK / TKA;     // 32 tiles
        for (int tile = 0; tile < NT; ++tile) {
            int cur = tile & 1;
            float4 ka, kb, va, vv;
            bool more = (tile + 1) < NT;
            if (more) {
                const float4* Kg = (const float4*)(K + (kbeg + (tile + 1) * TKA) * HID);
                const float4* Vg = (const float4*)(V + (kbeg + (tile + 1) * TKA) * HID);
                ka = Kg[t]; kb = Kg[t + 256];
                va = Vg[t]; vv = Vg[t + 256];
            }

            const float4* Kr0 = (const float4*)&smem.attn.Kl[cur][sub * KSTA + h * HDIM];
            const float4* Kr1 = (const float4*)&smem.attn.Kl[cur][(sub + 16) * KSTA + h * HDIM];
            float4 x0 = Kr0[0], x1 = Kr0[1], x2 = Kr0[2], x3 = Kr0[3];
            float4 y0 = Kr1[0], y1 = Kr1[1], y2 = Kr1[2], y3 = Kr1[3];

            float s0[4], s1[4];
#pragma unroll
            for (int qq = 0; qq < 4; ++qq) {
                s0[qq] = DOT4(x0, q4[qq][0]) + DOT4(x1, q4[qq][1]) + DOT4(x2, q4[qq][2]) + DOT4(x3, q4[qq][3]);
                s1[qq] = DOT4(y0, q4[qq][0]) + DOT4(y1, q4[qq][1]) + DOT4(y2, q4[qq][2]) + DOT4(y3, q4[qq][3]);
            }

            const float4* Vr0 = (const float4*)&smem.attn.Vl[cur][sub * KSTA + h * HDIM];
            const float4* Vr1 = (const float4*)&smem.attn.Vl[cur][(sub + 16) * KSTA + h * HDIM];
            float4 v00 = Vr0[0], v01 = Vr0[1], v02 = Vr0[2], v03 = Vr0[3];
            float4 v10 = Vr1[0], v11 = Vr1[1], v12 = Vr1[2], v13 = Vr1[3];

#pragma unroll
            for (int qq = 0; qq < 4; ++qq) {
                float mn = fmaxf(mreg[qq], fmaxf(s0[qq], s1[qq]));
                float al = EXP2(mreg[qq] - mn);
                float p0 = EXP2(s0[qq] - mn);
                float p1 = EXP2(s1[qq] - mn);
                lreg[qq] = lreg[qq] * al + p0 + p1;
                upd4(A[qq][0], v00, v10, p0, p1, al);
                upd4(A[qq][1], v01, v11, p0, p1, al);
                upd4(A[qq][2], v02, v12, p0, p1, al);
                upd4(A[qq][3], v03, v13, p0, p1, al);
                mreg[qq] = mn;
            }

            if (more) {
                int nxt = cur ^ 1;
                *(float4*)&smem.attn.Kl[nxt][r0 * KSTA + c0] = ka;
                *(float4*)&smem.attn.Kl[nxt][(r0 + 16) * KSTA + c0] = kb;
                *(float4*)&smem.attn.Vl[nxt][r0 * KSTA + c0] = va;
                *(float4*)&smem.attn.Vl[nxt][(r0 + 16) * KSTA + c0] = vv;
            }
            __syncthreads();
        }

#pragma unroll
        for (int off = 1; off < 16; off <<= 1) {
#pragma unroll
            for (int qq = 0; qq < 4; ++qq) {
                float m2 = __shfl_xor(mreg[qq], off, 64);
                float l2 = __shfl_xor(lreg[qq], off, 64);
                float4 B0 = shfl4(A[qq][0], off), B1 = shfl4(A[qq][1], off);
                float4 B2 = shfl4(A[qq][2], off), B3 = shfl4(A[qq][3], off);
                float mn = fmaxf(mreg[qq], m2);
                float c1 = EXP2(mreg[qq] - mn), c2 = EXP2(m2 - mn);
                lreg[qq] = lreg[qq] * c1 + l2 * c2;
                merge4(A[qq][0], B0, c1, c2); merge4(A[qq][1], B1, c1, c2);
                merge4(A[qq][2], B2, c1, c2); merge4(A[qq][3], B3, c1, c2);
                mreg[qq] = mn;
            }
        }

        if (sub == 0) {
#pragma unroll
            for (int qq = 0; qq < 4; ++qq) {
                int qi = q0 + qg * 4 + qq;
                float* pp = part + (size_t)((qi * HEADS + h) * CH + chunk) * 20;
                pp[0] = mreg[qq]; pp[1] = lreg[qq];
                *(float4*)&pp[4] = A[qq][0]; *(float4*)&pp[8] = A[qq][1];
                *(float4*)&pp[12] = A[qq][2]; *(float4*)&pp[16] = A[qq][3];
            }
        }
    }
    gg.sync();

    // ---- phase G: chunk-merge + residual + mean-pool + head (32 vb)
    for (int b = blockIdx.x; b < BATCH; b += nb) {
        int h = t & 3, s = t >> 2;
        int ms, me, ps, pe;
        {
            int lo = 0, hi = N_MOL;
            while (lo < hi) { int mid = (lo + hi) >> 1; if (p.mol_b[mid] < b) lo = mid + 1; else hi = mid; }
            ms = lo; lo = ms; hi = N_MOL;
            while (lo < hi) { int mid = (lo + hi) >> 1; if (p.mol_b[mid] < b + 1) lo = mid + 1; else hi = mid; }
            me = lo;
            lo = 0; hi = N_PROT;
            while (lo < hi) { int mid = (lo + hi) >> 1; if (p.prot_b[mid] < b) lo = mid + 1; else hi = mid; }
            ps = lo; lo = ps; hi = N_PROT;
            while (lo < hi) { int mid = (lo + hi) >> 1; if (p.prot_b[mid] < b + 1) lo = mid + 1; else hi = mid; }
            pe = lo;
        }
        __syncthreads();   // protect LDS union reuse
        // mol -> z[0..63]
        {
            float acc[16];
#pragma unroll
            for (int d = 0; d < 16; ++d) acc[d] = 0.f;
            for (int q = ms + s; q < me; q += 64) {
                const float* p0 = p.partm + (size_t)(q * HEADS + h) * CH_MOL * 20;
                float mmax = -INFINITY;
#pragma unroll
                for (int c = 0; c < CH_MOL; ++c) mmax = fmaxf(mmax, p0[c * 20]);
                float lsum = 0.f, wgt[CH_MOL];
#pragma unroll
                for (int c = 0; c < CH_MOL; ++c) {
                    wgt[c] = EXP2(p0[c * 20] - mmax);
                    lsum += p0[c * 20 + 1] * wgt[c];
                }
                float inv = 1.f / lsum;
                const float* Xr = p.xb_m + q * HID + h * HDIM;
#pragma unroll
                for (int d = 0; d < 16; ++d) {
                    float o = Xr[d];
#pragma unroll
                    for (int c = 0; c < CH_MOL; ++c)
                        o = fmaf(p0[c * 20 + 4 + d], wgt[c] * inv, o);
                    acc[d] += o;
                }
            }
#pragma unroll
            for (int d = 0; d < 16; ++d) smem.fin.red[s][h * 16 + d] = acc[d];
        }
        __syncthreads();
        if (t < 64) {
            float sum = 0.f;
            for (int ss = 0; ss < 64; ++ss) sum += smem.fin.red[ss][t];
            smem.fin.z[t] = sum / fmaxf((float)(me - ms), 1.f);
        }
        __syncthreads();
        // prot -> z[64..127]
        {
            float acc[16];
#pragma unroll
            for (int d = 0; d < 16; ++d) acc[d] = 0.f;
            for (int q = ps + s; q < pe; q += 64) {
                const float* p0 = p.partp + (size_t)(q * HEADS + h) * CH_PROT * 20;
                float m0 = p0[0], m1 = p0[20];
                float mmax = fmaxf(m0, m1);
                float w0 = EXP2(m0 - mmax), w1 = EXP2(m1 - mmax);
                float inv = 1.f / (p0[1] * w0 + p0[21] * w1);
                w0 *= inv; w1 *= inv;
                const float* Xr = p.xb_p + q * HID + h * HDIM;
#pragma unroll
                for (int d = 0; d < 16; ++d)
                    acc[d] += Xr[d] + p0[4 + d] * w0 + p0[24 + d] * w1;
            }
#pragma unroll
            for (int d = 0; d < 16; ++d) smem.fin.red[s][h * 16 + d] = acc[d];
        }
        __syncthreads();
        if (t < 64) {
            float sum = 0.f;
            for (int ss = 0; ss < 64; ++ss) sum += smem.fin.red[ss][t];
            smem.fin.z[64 + t] = sum / fmaxf((float)(pe - ps), 1.f);
        }
        __syncthreads();
        if (t < 64) {
            float acc = p.fc1b[t];
            const float4* zv = (const float4*)smem.fin.z;
#pragma unroll
            for (int k = 0; k < 32; ++k) {
                float4 hv = zv[k];
                acc = fmaf(hv.x, p.fc1W[(4 * k + 0) * 64 + t], acc);
                acc = fmaf(hv.y, p.fc1W[(4 * k + 1) * 64 + t], acc);
                acc = fmaf(hv.z, p.fc1W[(4 * k + 2) * 64 + t], acc);
                acc = fmaf(hv.w, p.fc1W[(4 * k + 3) * 64 + t], acc);
            }
            float hv = fmaxf(acc, 0.f);
            float prod = hv * p.fc2W[t];
#pragma unroll
            for (int off = 32; off > 0; off >>= 1) prod += __shfl_xor(prod, off, 64);
            if (t == 0) p.out[b] = 1.f / (1.f + __expf(-(prod + p.fc2b[0])));
        }
        __syncthreads();
    }
}

// ---------------------------------------------------------------------------
extern "C" void kernel_launch(void* const* d_in, const int* in_sizes, int n_in,
                              void* d_out, int out_size, void* d_ws, size_t ws_size,
                              hipStream_t stream) {
    Prm p;
    p.mol_x   = (const float*)d_in[0];
    p.prot_x  = (const float*)d_in[1];
    p.mol_ea  = (const float*)d_in[2];
    p.prot_ea = (const float*)d_in[3];
    p.mol_ei  = (const int*)d_in[4];
    p.prot_ei = (const int*)d_in[5];
    p.mol_b   = (const int*)d_in[6];
    p.prot_b  = (const int*)d_in[7];
    p.nlmW = (const float*)d_in[8];
    p.nlmb = (const float*)d_in[9];
    p.nlpW = (const float*)d_in[10];
    p.nlpb = (const float*)d_in[11];
    p.elmW = (const float*)d_in[12];
    p.elmb = (const float*)d_in[13];
    p.elpW = (const float*)d_in[14];
    p.elpb = (const float*)d_in[15];
    p.mcW1 = (const float*)d_in[16];
    p.mcb1 = (const float*)d_in[17];
    p.mcW2 = (const float*)d_in[18];
    p.mcb2 = (const float*)d_in[19];
    p.pcW1 = (const float*)d_in[20];
    p.pcb1 = (const float*)d_in[21];
    p.pcW2 = (const float*)d_in[22];
    p.pcb2 = (const float*)d_in[23];
    p.mpW  = (const float*)d_in[24];
    p.mpb  = (const float*)d_in[25];
    p.pmW  = (const float*)d_in[26];
    p.pmb  = (const float*)d_in[27];
    p.fc1W = (const float*)d_in[28];
    p.fc1b = (const float*)d_in[29];
    p.fc2W = (const float*)d_in[30];
    p.fc2b = (const float*)d_in[31];

    float* ws = (float*)d_ws;
    p.xa_m  = ws;
    p.xa_p  = p.xa_m + 131072;
    p.xb_m  = p.xa_p + 262144;
    p.xb_p  = p.xb_m + 131072;
    p.Qm    = p.xb_p + 262144;
    p.Kp    = p.Qm + 131072;
    p.Vp    = p.Kp + 262144;
    p.Qp    = p.Vp + 262144;
    p.Km    = p.Qp + 262144;
    p.Vm    = p.Km + 131072;
    p.partm = p.Vm + 131072;            // 2048*4*4*20 = 655360
    p.partp = p.partm + 655360;         // 4096*4*2*20 = 655360
    p.cursor = (int*)(p.partp + 655360);
    p.eidx  = (int*)p.partm;            // alias: eidx dead before partm written
    p.out   = (float*)d_out;

    int blocksPerCU = 0;
    hipOccupancyMaxActiveBlocksPerMultiprocessor(&blocksPerCU, (const void*)k_mega, 256, 0);
    if (blocksPerCU < 1) blocksPerCU = 1;
    int grid = blocksPerCU * 256;
    if (grid > 1024) grid = 1024;

    void* args[] = { &p };
    hipLaunchCooperativeKernel((void*)k_mega, dim3(grid), dim3(256), args, 0, stream);
}

// Round 11
// 374.163 us; speedup vs baseline: 3.7589x; 3.7589x over previous
//
#include <hip/hip_runtime.h>
#include <math.h>

#define HID 64
#define HEADS 4
#define HDIM 16
#define N_MOL 2048
#define N_PROT 4096
#define E_MOL 32768
#define E_PROT 131072
#define BATCH 32
#define N_TOT (N_MOL + N_PROT)
#define E_TOT (E_MOL + E_PROT)
#define CAP 128        // bucket capacity per node (mean deg 16/32; overflow prob ~0)

// attention tiling (r8-proven: 111us)
#define TQA 16         // queries per block
#define TKA 32         // keys per LDS tile
#define KSTA 68        // LDS row stride (words)
#define CH_MOL 4       // key chunks for mol queries (1024 keys each)
#define CH_PROT 2      // key chunks for prot queries (1024 keys each)
#define KCHUNK 1024
#define NGRP_MOL (N_MOL / TQA)          // 128

#define DOT4(a, b) ((a).x*(b).x + (a).y*(b).y + (a).z*(b).z + (a).w*(b).w)
#define EXP2(x) __builtin_amdgcn_exp2f(x)

// ---------------------------------------------------------------------------
// Fused node-linear + adjacency bucketing (independent work, one dispatch).
__global__ void k_nlb(const float* __restrict__ mol_x, const float* __restrict__ prot_x,
                      const float* __restrict__ Wm, const float* __restrict__ bm,
                      const float* __restrict__ Wp, const float* __restrict__ bp,
                      const int* __restrict__ mol_ei, const int* __restrict__ prot_ei,
                      float* __restrict__ xm, float* __restrict__ xp,
                      int* __restrict__ cursor, int* __restrict__ eidx) {
    if (blockIdx.x < N_TOT / 4) {
        int w = threadIdx.x >> 6, t = threadIdx.x & 63;
        int n = blockIdx.x * 4 + w;
        if (n < N_MOL) {
            const float* xr = mol_x + n * 11;
            float acc = bm[t];
#pragma unroll
            for (int i = 0; i < 11; ++i) acc += xr[i] * Wm[i * HID + t];
            xm[n * HID + t] = acc;
        } else {
            int p = n - N_MOL;
            const float* xr = prot_x + p * 15;
            float acc = bp[t];
#pragma unroll
            for (int i = 0; i < 15; ++i) acc += xr[i] * Wp[i * HID + t];
            xp[p * HID + t] = acc;
        }
    } else {
        int e = (blockIdx.x - N_TOT / 4) * 256 + threadIdx.x;
        int node, loc;
        if (e < E_MOL) { node = mol_ei[E_MOL + e]; loc = e; }
        else { int el = e - E_MOL; node = N_MOL + prot_ei[E_PROT + el]; loc = el; }
        int pos = atomicAdd(&cursor[node], 1);
        eidx[(size_t)node * CAP + pos] = loc;   // local edge id
    }
}

// ---------------------------------------------------------------------------
// Fused GINE layer: bucket gather + node MLP. 8 nodes/block, 2 per wave.
__global__ void k_gine(const float* __restrict__ xin_m, const float* __restrict__ xin_p,
                       float* __restrict__ xout_m, float* __restrict__ xout_p,
                       const float* __restrict__ mol_ea, const float* __restrict__ prot_ea,
                       const int* __restrict__ mol_ei, const int* __restrict__ prot_ei,
                       const float* __restrict__ Wem, const float* __restrict__ bem,
                       const float* __restrict__ Wep, const float* __restrict__ bep,
                       const float* __restrict__ W1m, const float* __restrict__ b1m,
                       const float* __restrict__ W2m, const float* __restrict__ b2m,
                       const float* __restrict__ W1p, const float* __restrict__ b1p,
                       const float* __restrict__ W2p, const float* __restrict__ b2p,
                       const int* __restrict__ cnt, const int* __restrict__ eidx) {
    __shared__ float h0[8][HID];
    __shared__ float h1[8][HID];
    int w = threadIdx.x >> 6, t = threadIdx.x & 63;
    int nb0 = blockIdx.x * 8 + w * 2;        // 2048 % 8 == 0: block is type-uniform
    bool isMol = nb0 < N_MOL;
    const float* x  = isMol ? xin_m : xin_p;
    float* xo       = isMol ? xout_m : xout_p;
    const float* We = isMol ? Wem : Wep;
    float bt        = isMol ? bem[t] : bep[t];
    const float* ea_base = isMol ? mol_ea : prot_ea;
    const int* srcarr    = isMol ? mol_ei : prot_ei;
    int nbias = isMol ? 0 : N_MOL;
    float wcol[10];
#pragma unroll
    for (int i = 0; i < 10; ++i) wcol[i] = We[i * HID + t];

#pragma unroll
    for (int u = 0; u < 2; ++u) {
        int nb = nb0 + u;
        int deg = cnt[nb];
        const int* lst = eidx + (size_t)nb * CAP;
        float agg = 0.f;
        int j = 0;
        for (; j + 1 < deg; j += 2) {
            int e0 = lst[j], e1 = lst[j + 1];
            int s0 = srcarr[e0], s1 = srcarr[e1];
            const float2* p0 = (const float2*)(ea_base + (size_t)e0 * 10);
            const float2* p1 = (const float2*)(ea_base + (size_t)e1 * 10);
            float2 a0 = p0[0], a1 = p0[1], a2 = p0[2], a3 = p0[3], a4 = p0[4];
            float2 c0 = p1[0], c1 = p1[1], c2 = p1[2], c3 = p1[3], c4 = p1[4];
            float xs0 = x[s0 * HID + t];
            float xs1 = x[s1 * HID + t];
            float m0 = bt, m1 = bt;
            m0 = fmaf(a0.x, wcol[0], m0); m0 = fmaf(a0.y, wcol[1], m0);
            m0 = fmaf(a1.x, wcol[2], m0); m0 = fmaf(a1.y, wcol[3], m0);
            m0 = fmaf(a2.x, wcol[4], m0); m0 = fmaf(a2.y, wcol[5], m0);
            m0 = fmaf(a3.x, wcol[6], m0); m0 = fmaf(a3.y, wcol[7], m0);
            m0 = fmaf(a4.x, wcol[8], m0); m0 = fmaf(a4.y, wcol[9], m0);
            m1 = fmaf(c0.x, wcol[0], m1); m1 = fmaf(c0.y, wcol[1], m1);
            m1 = fmaf(c1.x, wcol[2], m1); m1 = fmaf(c1.y, wcol[3], m1);
            m1 = fmaf(c2.x, wcol[4], m1); m1 = fmaf(c2.y, wcol[5], m1);
            m1 = fmaf(c3.x, wcol[6], m1); m1 = fmaf(c3.y, wcol[7], m1);
            m1 = fmaf(c4.x, wcol[8], m1); m1 = fmaf(c4.y, wcol[9], m1);
            agg += fmaxf(m0 + xs0, 0.f) + fmaxf(m1 + xs1, 0.f);
        }
        if (j < deg) {
            int e0 = lst[j];
            int s0 = srcarr[e0];
            const float2* p0 = (const float2*)(ea_base + (size_t)e0 * 10);
            float2 a0 = p0[0], a1 = p0[1], a2 = p0[2], a3 = p0[3], a4 = p0[4];
            float xs0 = x[s0 * HID + t];
            float m0 = bt;
            m0 = fmaf(a0.x, wcol[0], m0); m0 = fmaf(a0.y, wcol[1], m0);
            m0 = fmaf(a1.x, wcol[2], m0); m0 = fmaf(a1.y, wcol[3], m0);
            m0 = fmaf(a2.x, wcol[4], m0); m0 = fmaf(a2.y, wcol[5], m0);
            m0 = fmaf(a3.x, wcol[6], m0); m0 = fmaf(a3.y, wcol[7], m0);
            m0 = fmaf(a4.x, wcol[8], m0); m0 = fmaf(a4.y, wcol[9], m0);
            agg += fmaxf(m0 + xs0, 0.f);
        }
        h0[w * 2 + u][t] = x[(nb0 - nbias + u) * HID + t] + agg;
    }

    const float* W1 = isMol ? W1m : W1p;
    const float* W2 = isMol ? W2m : W2p;
    float b1v = isMol ? b1m[t] : b1p[t];
    float b2v = isMol ? b2m[t] : b2p[t];
    float acc0 = b1v, acc1 = b1v;
    const float4* hA = (const float4*)h0[w * 2];
    const float4* hB = (const float4*)h0[w * 2 + 1];
#pragma unroll
    for (int k = 0; k < 16; ++k) {
        float4 a = hA[k], b = hB[k];
        float w0 = W1[(4 * k + 0) * HID + t], w1 = W1[(4 * k + 1) * HID + t];
        float w2 = W1[(4 * k + 2) * HID + t], w3 = W1[(4 * k + 3) * HID + t];
        acc0 = fmaf(a.x, w0, acc0); acc1 = fmaf(b.x, w0, acc1);
        acc0 = fmaf(a.y, w1, acc0); acc1 = fmaf(b.y, w1, acc1);
        acc0 = fmaf(a.z, w2, acc0); acc1 = fmaf(b.z, w2, acc1);
        acc0 = fmaf(a.w, w3, acc0); acc1 = fmaf(b.w, w3, acc1);
    }
    h1[w * 2][t] = fmaxf(acc0, 0.f);
    h1[w * 2 + 1][t] = fmaxf(acc1, 0.f);
    float d0 = b2v, d1 = b2v;
    const float4* gA = (const float4*)h1[w * 2];
    const float4* gB = (const float4*)h1[w * 2 + 1];
#pragma unroll
    for (int k = 0; k < 16; ++k) {
        float4 a = gA[k], b = gB[k];
        float w0 = W2[(4 * k + 0) * HID + t], w1 = W2[(4 * k + 1) * HID + t];
        float w2 = W2[(4 * k + 2) * HID + t], w3 = W2[(4 * k + 3) * HID + t];
        d0 = fmaf(a.x, w0, d0); d1 = fmaf(b.x, w0, d1);
        d0 = fmaf(a.y, w1, d0); d1 = fmaf(b.y, w1, d1);
        d0 = fmaf(a.z, w2, d0); d1 = fmaf(b.z, w2, d1);
        d0 = fmaf(a.w, w3, d0); d1 = fmaf(b.w, w3, d1);
    }
    int n0 = nb0 - nbias;
    xo[n0 * HID + t] = fmaxf(d0, 0.f);
    xo[(n0 + 1) * HID + t] = fmaxf(d1, 0.f);
}

// ---------------------------------------------------------------------------
// QKV projections: 8 rows/block, 2 per wave (shared weight loads).
__global__ void k_qkv(const float* __restrict__ xm, const float* __restrict__ xp,
                      const float* __restrict__ mpW, const float* __restrict__ mpb,
                      const float* __restrict__ pmW, const float* __restrict__ pmb,
                      float* __restrict__ Qm, float* __restrict__ Kp, float* __restrict__ Vp,
                      float* __restrict__ Qp, float* __restrict__ Km, float* __restrict__ Vm) {
    __shared__ float row[8][HID];
    int w = threadIdx.x >> 6, t = threadIdx.x & 63;
    int b0 = blockIdx.x * 8;              // all segment bounds divisible by 8
    const float *src, *W, *bias;
    float* dst;
    int base;
    if (b0 < 2048)       { base = 0;     src = xm; W = mpW;        bias = mpb;       dst = Qm; }
    else if (b0 < 6144)  { base = 2048;  src = xp; W = mpW + 4096; bias = mpb + 64;  dst = Kp; }
    else if (b0 < 10240) { base = 6144;  src = xp; W = mpW + 8192; bias = mpb + 128; dst = Vp; }
    else if (b0 < 14336) { base = 10240; src = xp; W = pmW;        bias = pmb;       dst = Qp; }
    else if (b0 < 16384) { base = 14336; src = xm; W = pmW + 4096; bias = pmb + 64;  dst = Km; }
    else                 { base = 16384; src = xm; W = pmW + 8192; bias = pmb + 128; dst = Vm; }
    int n0 = b0 - base + w * 2, n1 = n0 + 1;
    row[w * 2][t] = src[n0 * HID + t];
    row[w * 2 + 1][t] = src[n1 * HID + t];
    float acc0 = bias[t], acc1 = acc0;
    const float4* rA = (const float4*)row[w * 2];
    const float4* rB = (const float4*)row[w * 2 + 1];
#pragma unroll
    for (int k = 0; k < 16; ++k) {
        float4 a = rA[k], b = rB[k];
        float w0 = W[(4 * k + 0) * HID + t], w1 = W[(4 * k + 1) * HID + t];
        float w2 = W[(4 * k + 2) * HID + t], w3 = W[(4 * k + 3) * HID + t];
        acc0 = fmaf(a.x, w0, acc0); acc1 = fmaf(b.x, w0, acc1);
        acc0 = fmaf(a.y, w1, acc0); acc1 = fmaf(b.y, w1, acc1);
        acc0 = fmaf(a.z, w2, acc0); acc1 = fmaf(b.z, w2, acc1);
        acc0 = fmaf(a.w, w3, acc0); acc1 = fmaf(b.w, w3, acc1);
    }
    dst[n0 * HID + t] = acc0;
    dst[n1 * HID + t] = acc1;
}

// ---------------------------------------------------------------------------
__device__ inline void upd4(float4& A, const float4 v0, const float4 v1,
                            float p0, float p1, float al) {
    A.x = fmaf(p1, v1.x, fmaf(p0, v0.x, A.x * al));
    A.y = fmaf(p1, v1.y, fmaf(p0, v0.y, A.y * al));
    A.z = fmaf(p1, v1.z, fmaf(p0, v0.z, A.z * al));
    A.w = fmaf(p1, v1.w, fmaf(p0, v0.w, A.w * al));
}
__device__ inline void merge4(float4& A, const float4 B, float c1, float c2) {
    A.x = A.x * c1 + B.x * c2;
    A.y = A.y * c1 + B.y * c2;
    A.z = A.z * c1 + B.z * c2;
    A.w = A.w * c1 + B.w * c2;
}
__device__ inline float4 shfl4(const float4 a, int off) {
    float4 r;
    r.x = __shfl_xor(a.x, off, 64); r.y = __shfl_xor(a.y, off, 64);
    r.z = __shfl_xor(a.z, off, 64); r.w = __shfl_xor(a.w, off, 64);
    return r;
}

// ---------------------------------------------------------------------------
// Tiled cross attention (r8-proven config): Q_LOCAL=4, double-buffered LDS,
// base-2 softmax via raw v_exp_f32, CH_MOL=4 / CH_PROT=2 (1024 keys/block).
__global__ __launch_bounds__(256) void k_attn(
    const float* __restrict__ Qm, const float* __restrict__ Kp, const float* __restrict__ Vp,
    const float* __restrict__ Qp, const float* __restrict__ Km, const float* __restrict__ Vm,
    float* __restrict__ part_m, float* __restrict__ part_p) {
    __shared__ float Kl[2][TKA * KSTA];
    __shared__ float Vl[2][TKA * KSTA];

    int t = threadIdx.x;
    const float *Q, *K, *V;
    float* part;
    int q0, chunk, CH;
    {
        int b = blockIdx.x;
        const int MOLB = NGRP_MOL * CH_MOL;   // 512
        if (b < MOLB) {
            chunk = b & 3; q0 = (b >> 2) * TQA; CH = CH_MOL;
            Q = Qm; K = Kp; V = Vp; part = part_m;
        } else {
            b -= MOLB;
            chunk = b & 1; q0 = (b >> 1) * TQA; CH = CH_PROT;
            Q = Qp; K = Km; V = Vm; part = part_p;
        }
    }
    int kbeg = chunk * KCHUNK;

    int sub = t & 15, h = (t >> 4) & 3, qg = t >> 6;
    int r0 = t >> 4;                 // staging row 0..15 (and r0+16)
    int c0 = (t & 15) << 2;          // staging col (words)

    const float sc = 0.25f * 1.44269504088896f;   // 1/sqrt(16) * log2(e)
    float4 q4[4][4];
#pragma unroll
    for (int qq = 0; qq < 4; ++qq) {
        const float4* Qr = (const float4*)(Q + (q0 + qg * 4 + qq) * HID + h * HDIM);
#pragma unroll
        for (int j = 0; j < 4; ++j) {
            float4 v = Qr[j];
            v.x *= sc; v.y *= sc; v.z *= sc; v.w *= sc;
            q4[qq][j] = v;
        }
    }

    float mreg[4], lreg[4];
    float4 A[4][4];
#pragma unroll
    for (int qq = 0; qq < 4; ++qq) {
        mreg[qq] = -INFINITY; lreg[qq] = 0.f;
#pragma unroll
        for (int j = 0; j < 4; ++j) A[qq][j] = (float4){0.f, 0.f, 0.f, 0.f};
    }

    // prologue: stage tile 0 into buffer 0
    {
        const float4* Kg = (const float4*)(K + kbeg * HID);
        const float4* Vg = (const float4*)(V + kbeg * HID);
        float4 ka = Kg[t], kb = Kg[t + 256];
        float4 va = Vg[t], vb = Vg[t + 256];
        *(float4*)&Kl[0][r0 * KSTA + c0] = ka;
        *(float4*)&Kl[0][(r0 + 16) * KSTA + c0] = kb;
        *(float4*)&Vl[0][r0 * KSTA + c0] = va;
        *(float4*)&Vl[0][(r0 + 16) * KSTA + c0] = vb;
    }
    __syncthreads();

    const int NT = KCHUNK / TKA;     // 32 tiles
    for (int tile = 0; tile < NT; ++tile) {
        int cur = tile & 1;
        float4 ka, kb, va, vb;
        bool more = (tile + 1) < NT;
        if (more) {
            const float4* Kg = (const float4*)(K + (kbeg + (tile + 1) * TKA) * HID);
            const float4* Vg = (const float4*)(V + (kbeg + (tile + 1) * TKA) * HID);
            ka = Kg[t]; kb = Kg[t + 256];
            va = Vg[t]; vb = Vg[t + 256];
        }

        const float4* Kr0 = (const float4*)&Kl[cur][sub * KSTA + h * HDIM];
        const float4* Kr1 = (const float4*)&Kl[cur][(sub + 16) * KSTA + h * HDIM];
        float4 x0 = Kr0[0], x1 = Kr0[1], x2 = Kr0[2], x3 = Kr0[3];
        float4 y0 = Kr1[0], y1 = Kr1[1], y2 = Kr1[2], y3 = Kr1[3];

        float s0[4], s1[4];
#pragma unroll
        for (int qq = 0; qq < 4; ++qq) {
            s0[qq] = DOT4(x0, q4[qq][0]) + DOT4(x1, q4[qq][1]) + DOT4(x2, q4[qq][2]) + DOT4(x3, q4[qq][3]);
            s1[qq] = DOT4(y0, q4[qq][0]) + DOT4(y1, q4[qq][1]) + DOT4(y2, q4[qq][2]) + DOT4(y3, q4[qq][3]);
        }

        const float4* Vr0 = (const float4*)&Vl[cur][sub * KSTA + h * HDIM];
        const float4* Vr1 = (const float4*)&Vl[cur][(sub + 16) * KSTA + h * HDIM];
        float4 v00 = Vr0[0], v01 = Vr0[1], v02 = Vr0[2], v03 = Vr0[3];
        float4 v10 = Vr1[0], v11 = Vr1[1], v12 = Vr1[2], v13 = Vr1[3];

#pragma unroll
        for (int qq = 0; qq < 4; ++qq) {
            float mn = fmaxf(mreg[qq], fmaxf(s0[qq], s1[qq]));
            float al = EXP2(mreg[qq] - mn);
            float p0 = EXP2(s0[qq] - mn);
            float p1 = EXP2(s1[qq] - mn);
            lreg[qq] = lreg[qq] * al + p0 + p1;
            upd4(A[qq][0], v00, v10, p0, p1, al);
            upd4(A[qq][1], v01, v11, p0, p1, al);
            upd4(A[qq][2], v02, v12, p0, p1, al);
            upd4(A[qq][3], v03, v13, p0, p1, al);
            mreg[qq] = mn;
        }

        if (more) {
            int nxt = cur ^ 1;
            *(float4*)&Kl[nxt][r0 * KSTA + c0] = ka;
            *(float4*)&Kl[nxt][(r0 + 16) * KSTA + c0] = kb;
            *(float4*)&Vl[nxt][r0 * KSTA + c0] = va;
            *(float4*)&Vl[nxt][(r0 + 16) * KSTA + c0] = vb;
        }
        __syncthreads();
    }

    // merge 16 partial states across sub lanes (lane bits 0..3)
#pragma unroll
    for (int off = 1; off < 16; off <<= 1) {
#pragma unroll
        for (int qq = 0; qq < 4; ++qq) {
            float m2 = __shfl_xor(mreg[qq], off, 64);
            float l2 = __shfl_xor(lreg[qq], off, 64);
            float4 B0 = shfl4(A[qq][0], off), B1 = shfl4(A[qq][1], off);
            float4 B2 = shfl4(A[qq][2], off), B3 = shfl4(A[qq][3], off);
            float mn = fmaxf(mreg[qq], m2);
            float c1 = EXP2(mreg[qq] - mn), c2 = EXP2(m2 - mn);
            lreg[qq] = lreg[qq] * c1 + l2 * c2;
            merge4(A[qq][0], B0, c1, c2); merge4(A[qq][1], B1, c1, c2);
            merge4(A[qq][2], B2, c1, c2); merge4(A[qq][3], B3, c1, c2);
            mreg[qq] = mn;
        }
    }

    if (sub == 0) {
#pragma unroll
        for (int qq = 0; qq < 4; ++qq) {
            int qi = q0 + qg * 4 + qq;
            float* pp = part + (size_t)((qi * HEADS + h) * CH + chunk) * 20;
            pp[0] = mreg[qq]; pp[1] = lreg[qq];
            *(float4*)&pp[4] = A[qq][0]; *(float4*)&pp[8] = A[qq][1];
            *(float4*)&pp[12] = A[qq][2]; *(float4*)&pp[16] = A[qq][3];
        }
    }
}

// ---------------------------------------------------------------------------
// Fused chunk-merge + residual + mean-pool + MLP head (r9-proven). One block
// per batch; H never materialized. Thread t: head h=t&3, node-slot s=t>>2.
__global__ void k_final(const float* __restrict__ part_m, const float* __restrict__ part_p,
                        const float* __restrict__ xm, const float* __restrict__ xp,
                        const int* __restrict__ mb, const int* __restrict__ pb,
                        const float* __restrict__ fc1W, const float* __restrict__ fc1b,
                        const float* __restrict__ fc2W, const float* __restrict__ fc2b,
                        float* __restrict__ out) {
    __shared__ float sm[64][65];
    __shared__ float z[2 * HID];
    int b = blockIdx.x;
    int t = threadIdx.x;
    int h = t & 3, s = t >> 2;
    int ms, me, ps, pe;
    {
        int lo = 0, hi = N_MOL;
        while (lo < hi) { int mid = (lo + hi) >> 1; if (mb[mid] < b) lo = mid + 1; else hi = mid; }
        ms = lo; lo = ms; hi = N_MOL;
        while (lo < hi) { int mid = (lo + hi) >> 1; if (mb[mid] < b + 1) lo = mid + 1; else hi = mid; }
        me = lo;
        lo = 0; hi = N_PROT;
        while (lo < hi) { int mid = (lo + hi) >> 1; if (pb[mid] < b) lo = mid + 1; else hi = mid; }
        ps = lo; lo = ps; hi = N_PROT;
        while (lo < hi) { int mid = (lo + hi) >> 1; if (pb[mid] < b + 1) lo = mid + 1; else hi = mid; }
        pe = lo;
    }

    // ---- phase 1: mol (CH_MOL chunks) -> z[0..63]
    {
        float acc[16];
#pragma unroll
        for (int d = 0; d < 16; ++d) acc[d] = 0.f;
        for (int q = ms + s; q < me; q += 64) {
            const float* p0 = part_m + (size_t)(q * HEADS + h) * CH_MOL * 20;
            float mmax = -INFINITY;
#pragma unroll
            for (int c = 0; c < CH_MOL; ++c) mmax = fmaxf(mmax, p0[c * 20]);
            float lsum = 0.f, wgt[CH_MOL];
#pragma unroll
            for (int c = 0; c < CH_MOL; ++c) {
                wgt[c] = EXP2(p0[c * 20] - mmax);
                lsum += p0[c * 20 + 1] * wgt[c];
            }
            float inv = 1.f / lsum;
            const float* Xr = xm + q * HID + h * HDIM;
#pragma unroll
            for (int d = 0; d < 16; ++d) {
                float o = Xr[d];
#pragma unroll
                for (int c = 0; c < CH_MOL; ++c)
                    o = fmaf(p0[c * 20 + 4 + d], wgt[c] * inv, o);
                acc[d] += o;
            }
        }
#pragma unroll
        for (int d = 0; d < 16; ++d) sm[s][h * 16 + d] = acc[d];
    }
    __syncthreads();
    if (t < 64) {
        float sum = 0.f;
        for (int ss = 0; ss < 64; ++ss) sum += sm[ss][t];
        z[t] = sum / fmaxf((float)(me - ms), 1.f);
    }
    __syncthreads();

    // ---- phase 2: prot (CH_PROT chunks) -> z[64..127]
    {
        float acc[16];
#pragma unroll
        for (int d = 0; d < 16; ++d) acc[d] = 0.f;
        for (int q = ps + s; q < pe; q += 64) {
            const float* p0 = part_p + (size_t)(q * HEADS + h) * CH_PROT * 20;
            float m0 = p0[0], m1 = p0[20];
            float mmax = fmaxf(m0, m1);
            float w0 = EXP2(m0 - mmax), w1 = EXP2(m1 - mmax);
            float inv = 1.f / (p0[1] * w0 + p0[21] * w1);
            w0 *= inv; w1 *= inv;
            const float* Xr = xp + q * HID + h * HDIM;
#pragma unroll
            for (int d = 0; d < 16; ++d)
                acc[d] += Xr[d] + p0[4 + d] * w0 + p0[24 + d] * w1;
        }
#pragma unroll
        for (int d = 0; d < 16; ++d) sm[s][h * 16 + d] = acc[d];
    }
    __syncthreads();
    if (t < 64) {
        float sum = 0.f;
        for (int ss = 0; ss < 64; ++ss) sum += sm[ss][t];
        z[64 + t] = sum / fmaxf((float)(pe - ps), 1.f);
    }
    __syncthreads();

    // ---- head
    if (t < 64) {
        float acc = fc1b[t];
        const float4* zv = (const float4*)z;
#pragma unroll
        for (int k = 0; k < 32; ++k) {
            float4 hv = zv[k];
            acc = fmaf(hv.x, fc1W[(4 * k + 0) * 64 + t], acc);
            acc = fmaf(hv.y, fc1W[(4 * k + 1) * 64 + t], acc);
            acc = fmaf(hv.z, fc1W[(4 * k + 2) * 64 + t], acc);
            acc = fmaf(hv.w, fc1W[(4 * k + 3) * 64 + t], acc);
        }
        float hv = fmaxf(acc, 0.f);
        float prod = hv * fc2W[t];
#pragma unroll
        for (int off = 32; off > 0; off >>= 1) prod += __shfl_xor(prod, off, 64);
        if (t == 0) out[b] = 1.f / (1.f + __expf(-(prod + fc2b[0])));
    }
}

// ---------------------------------------------------------------------------
extern "C" void kernel_launch(void* const* d_in, const int* in_sizes, int n_in,
                              void* d_out, int out_size, void* d_ws, size_t ws_size,
                              hipStream_t stream) {
    const float* mol_x   = (const float*)d_in[0];
    const float* prot_x  = (const float*)d_in[1];
    const float* mol_ea  = (const float*)d_in[2];
    const float* prot_ea = (const float*)d_in[3];
    const int*   mol_ei  = (const int*)d_in[4];
    const int*   prot_ei = (const int*)d_in[5];
    const int*   mol_b   = (const int*)d_in[6];
    const int*   prot_b  = (const int*)d_in[7];
    const float* nlmW = (const float*)d_in[8];
    const float* nlmb = (const float*)d_in[9];
    const float* nlpW = (const float*)d_in[10];
    const float* nlpb = (const float*)d_in[11];
    const float* elmW = (const float*)d_in[12];
    const float* elmb = (const float*)d_in[13];
    const float* elpW = (const float*)d_in[14];
    const float* elpb = (const float*)d_in[15];
    const float* mcW1 = (const float*)d_in[16];
    const float* mcb1 = (const float*)d_in[17];
    const float* mcW2 = (const float*)d_in[18];
    const float* mcb2 = (const float*)d_in[19];
    const float* pcW1 = (const float*)d_in[20];
    const float* pcb1 = (const float*)d_in[21];
    const float* pcW2 = (const float*)d_in[22];
    const float* pcb2 = (const float*)d_in[23];
    const float* mpW  = (const float*)d_in[24];
    const float* mpb  = (const float*)d_in[25];
    const float* pmW  = (const float*)d_in[26];
    const float* pmb  = (const float*)d_in[27];
    const float* fc1W = (const float*)d_in[28];
    const float* fc1b = (const float*)d_in[29];
    const float* fc2W = (const float*)d_in[30];
    const float* fc2b = (const float*)d_in[31];

    float* ws    = (float*)d_ws;
    float* xa_m  = ws;                  // 131072
    float* xa_p  = xa_m + 131072;       // 262144
    float* xb_m  = xa_p + 262144;       // 131072
    float* xb_p  = xb_m + 131072;       // 262144
    float* Qm    = xb_p + 262144;       // 131072
    float* Kp    = Qm + 131072;         // 262144
    float* Vp    = Kp + 262144;         // 262144
    float* Qp    = Vp + 262144;         // 262144
    float* Km    = Qp + 262144;         // 131072
    float* Vm    = Km + 131072;         // 131072
    float* partm = Vm + 131072;         // 2048*4*4*20 = 655360
    float* partp = partm + 655360;      // 4096*4*2*20 = 655360
    int* cursor  = (int*)(partp + 655360);  // 6144
    // eidx aliases partm: used only before k_attn (3.1 MB < 5.2 MB)
    int* eidx    = (int*)partm;

    hipMemsetAsync(cursor, 0, (size_t)N_TOT * 4, stream);

    k_nlb<<<N_TOT / 4 + E_TOT / 256, 256, 0, stream>>>(
        mol_x, prot_x, nlmW, nlmb, nlpW, nlpb, mol_ei, prot_ei, xa_m, xa_p, cursor, eidx);

    k_gine<<<N_TOT / 8, 256, 0, stream>>>(xa_m, xa_p, xb_m, xb_p, mol_ea, prot_ea, mol_ei, prot_ei,
        elmW, elmb, elpW, elpb,
        mcW1, mcb1, mcW2, mcb2, pcW1, pcb1, pcW2, pcb2, cursor, eidx);
    k_gine<<<N_TOT / 8, 256, 0, stream>>>(xb_m, xb_p, xa_m, xa_p, mol_ea, prot_ea, mol_ei, prot_ei,
        elmW, elmb, elpW, elpb,
        mcW1 + 4096, mcb1 + 64, mcW2 + 4096, mcb2 + 64,
        pcW1 + 4096, pcb1 + 64, pcW2 + 4096, pcb2 + 64, cursor, eidx);
    k_gine<<<N_TOT / 8, 256, 0, stream>>>(xa_m, xa_p, xb_m, xb_p, mol_ea, prot_ea, mol_ei, prot_ei,
        elmW, elmb, elpW, elpb,
        mcW1 + 8192, mcb1 + 128, mcW2 + 8192, mcb2 + 128,
        pcW1 + 8192, pcb1 + 128, pcW2 + 8192, pcb2 + 128, cursor, eidx);

    k_qkv<<<18432 / 8, 256, 0, stream>>>(xb_m, xb_p, mpW, mpb, pmW, pmb, Qm, Kp, Vp, Qp, Km, Vm);
    k_attn<<<NGRP_MOL * CH_MOL + (N_PROT / TQA) * CH_PROT, 256, 0, stream>>>(
        Qm, Kp, Vp, Qp, Km, Vm, partm, partp);

    k_final<<<BATCH, 256, 0, stream>>>(partm, partp, xb_m, xb_p, mol_b, prot_b,
                                       fc1W, fc1b, fc2W, fc2b, (float*)d_out);
}

// Round 12
// 371.470 us; speedup vs baseline: 3.7862x; 1.0072x over previous
//
#include <hip/hip_runtime.h>
#include <math.h>

#define HID 64
#define HEADS 4
#define HDIM 16
#define N_MOL 2048
#define N_PROT 4096
#define E_MOL 32768
#define E_PROT 131072
#define BATCH 32
#define N_TOT (N_MOL + N_PROT)
#define E_TOT (E_MOL + E_PROT)
#define CAP 128        // bucket capacity per node (mean deg 16/32; overflow prob ~0)

// attention tiling (r8-proven: 111us)
#define TQA 16         // queries per block
#define TKA 32         // keys per LDS tile
#define KSTA 68        // LDS row stride (words)
#define CH_MOL 4       // key chunks for mol queries (1024 keys each)
#define CH_PROT 2      // key chunks for prot queries (1024 keys each)
#define KCHUNK 1024
#define NGRP_MOL (N_MOL / TQA)          // 128

#define DOT4(a, b) ((a).x*(b).x + (a).y*(b).y + (a).z*(b).z + (a).w*(b).w)
#define EXP2(x) __builtin_amdgcn_exp2f(x)

// ---------------------------------------------------------------------------
// Fused node-linear + adjacency bucketing (independent work, one dispatch).
__global__ void k_nlb(const float* __restrict__ mol_x, const float* __restrict__ prot_x,
                      const float* __restrict__ Wm, const float* __restrict__ bm,
                      const float* __restrict__ Wp, const float* __restrict__ bp,
                      const int* __restrict__ mol_ei, const int* __restrict__ prot_ei,
                      float* __restrict__ xm, float* __restrict__ xp,
                      int* __restrict__ cursor, int* __restrict__ eidx) {
    if (blockIdx.x < N_TOT / 4) {
        int w = threadIdx.x >> 6, t = threadIdx.x & 63;
        int n = blockIdx.x * 4 + w;
        if (n < N_MOL) {
            const float* xr = mol_x + n * 11;
            float acc = bm[t];
#pragma unroll
            for (int i = 0; i < 11; ++i) acc += xr[i] * Wm[i * HID + t];
            xm[n * HID + t] = acc;
        } else {
            int p = n - N_MOL;
            const float* xr = prot_x + p * 15;
            float acc = bp[t];
#pragma unroll
            for (int i = 0; i < 15; ++i) acc += xr[i] * Wp[i * HID + t];
            xp[p * HID + t] = acc;
        }
    } else {
        int e = (blockIdx.x - N_TOT / 4) * 256 + threadIdx.x;
        int node, loc;
        if (e < E_MOL) { node = mol_ei[E_MOL + e]; loc = e; }
        else { int el = e - E_MOL; node = N_MOL + prot_ei[E_PROT + el]; loc = el; }
        int pos = atomicAdd(&cursor[node], 1);
        eidx[(size_t)node * CAP + pos] = loc;   // local edge id
    }
}

// ---------------------------------------------------------------------------
// Fused GINE layer: bucket gather + node MLP. 8 nodes/block, 2 per wave.
// doProj (layer 3): also emits the wave's 2 rows' QKV projections (weight
// loads shared) — removes the separate k_qkv dispatch + x re-read.
__global__ void k_gine(const float* __restrict__ xin_m, const float* __restrict__ xin_p,
                       float* __restrict__ xout_m, float* __restrict__ xout_p,
                       const float* __restrict__ mol_ea, const float* __restrict__ prot_ea,
                       const int* __restrict__ mol_ei, const int* __restrict__ prot_ei,
                       const float* __restrict__ Wem, const float* __restrict__ bem,
                       const float* __restrict__ Wep, const float* __restrict__ bep,
                       const float* __restrict__ W1m, const float* __restrict__ b1m,
                       const float* __restrict__ W2m, const float* __restrict__ b2m,
                       const float* __restrict__ W1p, const float* __restrict__ b1p,
                       const float* __restrict__ W2p, const float* __restrict__ b2p,
                       const int* __restrict__ cnt, const int* __restrict__ eidx,
                       int doProj,
                       const float* __restrict__ mpW, const float* __restrict__ mpb,
                       const float* __restrict__ pmW, const float* __restrict__ pmb,
                       float* __restrict__ Qm, float* __restrict__ Kp, float* __restrict__ Vp,
                       float* __restrict__ Qp, float* __restrict__ Km, float* __restrict__ Vm) {
    __shared__ float h0[8][HID];
    __shared__ float h1[8][HID];
    int w = threadIdx.x >> 6, t = threadIdx.x & 63;
    int nb0 = blockIdx.x * 8 + w * 2;        // 2048 % 8 == 0: block is type-uniform
    bool isMol = nb0 < N_MOL;
    const float* x  = isMol ? xin_m : xin_p;
    float* xo       = isMol ? xout_m : xout_p;
    const float* We = isMol ? Wem : Wep;
    float bt        = isMol ? bem[t] : bep[t];
    const float* ea_base = isMol ? mol_ea : prot_ea;
    const int* srcarr    = isMol ? mol_ei : prot_ei;
    int nbias = isMol ? 0 : N_MOL;
    float wcol[10];
#pragma unroll
    for (int i = 0; i < 10; ++i) wcol[i] = We[i * HID + t];

#pragma unroll
    for (int u = 0; u < 2; ++u) {
        int nb = nb0 + u;
        int deg = cnt[nb];
        const int* lst = eidx + (size_t)nb * CAP;
        float agg = 0.f;
        int j = 0;
        for (; j + 1 < deg; j += 2) {
            int e0 = lst[j], e1 = lst[j + 1];
            int s0 = srcarr[e0], s1 = srcarr[e1];
            const float2* p0 = (const float2*)(ea_base + (size_t)e0 * 10);
            const float2* p1 = (const float2*)(ea_base + (size_t)e1 * 10);
            float2 a0 = p0[0], a1 = p0[1], a2 = p0[2], a3 = p0[3], a4 = p0[4];
            float2 c0 = p1[0], c1 = p1[1], c2 = p1[2], c3 = p1[3], c4 = p1[4];
            float xs0 = x[s0 * HID + t];
            float xs1 = x[s1 * HID + t];
            float m0 = bt, m1 = bt;
            m0 = fmaf(a0.x, wcol[0], m0); m0 = fmaf(a0.y, wcol[1], m0);
            m0 = fmaf(a1.x, wcol[2], m0); m0 = fmaf(a1.y, wcol[3], m0);
            m0 = fmaf(a2.x, wcol[4], m0); m0 = fmaf(a2.y, wcol[5], m0);
            m0 = fmaf(a3.x, wcol[6], m0); m0 = fmaf(a3.y, wcol[7], m0);
            m0 = fmaf(a4.x, wcol[8], m0); m0 = fmaf(a4.y, wcol[9], m0);
            m1 = fmaf(c0.x, wcol[0], m1); m1 = fmaf(c0.y, wcol[1], m1);
            m1 = fmaf(c1.x, wcol[2], m1); m1 = fmaf(c1.y, wcol[3], m1);
            m1 = fmaf(c2.x, wcol[4], m1); m1 = fmaf(c2.y, wcol[5], m1);
            m1 = fmaf(c3.x, wcol[6], m1); m1 = fmaf(c3.y, wcol[7], m1);
            m1 = fmaf(c4.x, wcol[8], m1); m1 = fmaf(c4.y, wcol[9], m1);
            agg += fmaxf(m0 + xs0, 0.f) + fmaxf(m1 + xs1, 0.f);
        }
        if (j < deg) {
            int e0 = lst[j];
            int s0 = srcarr[e0];
            const float2* p0 = (const float2*)(ea_base + (size_t)e0 * 10);
            float2 a0 = p0[0], a1 = p0[1], a2 = p0[2], a3 = p0[3], a4 = p0[4];
            float xs0 = x[s0 * HID + t];
            float m0 = bt;
            m0 = fmaf(a0.x, wcol[0], m0); m0 = fmaf(a0.y, wcol[1], m0);
            m0 = fmaf(a1.x, wcol[2], m0); m0 = fmaf(a1.y, wcol[3], m0);
            m0 = fmaf(a2.x, wcol[4], m0); m0 = fmaf(a2.y, wcol[5], m0);
            m0 = fmaf(a3.x, wcol[6], m0); m0 = fmaf(a3.y, wcol[7], m0);
            m0 = fmaf(a4.x, wcol[8], m0); m0 = fmaf(a4.y, wcol[9], m0);
            agg += fmaxf(m0 + xs0, 0.f);
        }
        h0[w * 2 + u][t] = x[(nb0 - nbias + u) * HID + t] + agg;
    }

    const float* W1 = isMol ? W1m : W1p;
    const float* W2 = isMol ? W2m : W2p;
    float b1v = isMol ? b1m[t] : b1p[t];
    float b2v = isMol ? b2m[t] : b2p[t];
    float acc0 = b1v, acc1 = b1v;
    const float4* hA = (const float4*)h0[w * 2];
    const float4* hB = (const float4*)h0[w * 2 + 1];
#pragma unroll
    for (int k = 0; k < 16; ++k) {
        float4 a = hA[k], b = hB[k];
        float w0 = W1[(4 * k + 0) * HID + t], w1 = W1[(4 * k + 1) * HID + t];
        float w2 = W1[(4 * k + 2) * HID + t], w3 = W1[(4 * k + 3) * HID + t];
        acc0 = fmaf(a.x, w0, acc0); acc1 = fmaf(b.x, w0, acc1);
        acc0 = fmaf(a.y, w1, acc0); acc1 = fmaf(b.y, w1, acc1);
        acc0 = fmaf(a.z, w2, acc0); acc1 = fmaf(b.z, w2, acc1);
        acc0 = fmaf(a.w, w3, acc0); acc1 = fmaf(b.w, w3, acc1);
    }
    h1[w * 2][t] = fmaxf(acc0, 0.f);
    h1[w * 2 + 1][t] = fmaxf(acc1, 0.f);
    float d0 = b2v, d1 = b2v;
    const float4* gA = (const float4*)h1[w * 2];
    const float4* gB = (const float4*)h1[w * 2 + 1];
#pragma unroll
    for (int k = 0; k < 16; ++k) {
        float4 a = gA[k], b = gB[k];
        float w0 = W2[(4 * k + 0) * HID + t], w1 = W2[(4 * k + 1) * HID + t];
        float w2 = W2[(4 * k + 2) * HID + t], w3 = W2[(4 * k + 3) * HID + t];
        d0 = fmaf(a.x, w0, d0); d1 = fmaf(b.x, w0, d1);
        d0 = fmaf(a.y, w1, d0); d1 = fmaf(b.y, w1, d1);
        d0 = fmaf(a.z, w2, d0); d1 = fmaf(b.z, w2, d1);
        d0 = fmaf(a.w, w3, d0); d1 = fmaf(b.w, w3, d1);
    }
    int n0 = nb0 - nbias;
    float xv0 = fmaxf(d0, 0.f), xv1 = fmaxf(d1, 0.f);
    xo[n0 * HID + t] = xv0;
    xo[(n0 + 1) * HID + t] = xv1;

    if (doProj) {
        // row-local QKV. mol rows feed Qm (mp.Q), Km (pm.K), Vm (pm.V);
        // prot rows feed Qp (pm.Q), Kp (mp.K), Vp (mp.V).  (r5-verified map)
        h0[w * 2][t] = xv0;                 // per-wave slice reuse, no barrier
        h0[w * 2 + 1][t] = xv1;
        const float *WQ, *bQ, *WK, *bK, *WV, *bV;
        float *dQ, *dK, *dV;
        if (isMol) { WQ = mpW;        bQ = mpb;       WK = pmW + 4096; bK = pmb + 64;
                     WV = pmW + 8192; bV = pmb + 128; dQ = Qm; dK = Km; dV = Vm; }
        else       { WQ = pmW;        bQ = pmb;       WK = mpW + 4096; bK = mpb + 64;
                     WV = mpW + 8192; bV = mpb + 128; dQ = Qp; dK = Kp; dV = Vp; }
        float aQ0 = bQ[t], aQ1 = aQ0;
        float aK0 = bK[t], aK1 = aK0;
        float aV0 = bV[t], aV1 = aV0;
        const float4* rA = (const float4*)h0[w * 2];
        const float4* rB = (const float4*)h0[w * 2 + 1];
#pragma unroll
        for (int k = 0; k < 16; ++k) {
            float4 a = rA[k], b = rB[k];
#pragma unroll
            for (int j = 0; j < 4; ++j) {
                float av = (j == 0) ? a.x : (j == 1) ? a.y : (j == 2) ? a.z : a.w;
                float bv = (j == 0) ? b.x : (j == 1) ? b.y : (j == 2) ? b.z : b.w;
                float wq = WQ[(4 * k + j) * HID + t];
                float wk = WK[(4 * k + j) * HID + t];
                float wv = WV[(4 * k + j) * HID + t];
                aQ0 = fmaf(av, wq, aQ0); aQ1 = fmaf(bv, wq, aQ1);
                aK0 = fmaf(av, wk, aK0); aK1 = fmaf(bv, wk, aK1);
                aV0 = fmaf(av, wv, aV0); aV1 = fmaf(bv, wv, aV1);
            }
        }
        dQ[n0 * HID + t] = aQ0; dQ[(n0 + 1) * HID + t] = aQ1;
        dK[n0 * HID + t] = aK0; dK[(n0 + 1) * HID + t] = aK1;
        dV[n0 * HID + t] = aV0; dV[(n0 + 1) * HID + t] = aV1;
    }
}

// ---------------------------------------------------------------------------
__device__ inline void upd4(float4& A, const float4 v0, const float4 v1,
                            float p0, float p1, float al) {
    A.x = fmaf(p1, v1.x, fmaf(p0, v0.x, A.x * al));
    A.y = fmaf(p1, v1.y, fmaf(p0, v0.y, A.y * al));
    A.z = fmaf(p1, v1.z, fmaf(p0, v0.z, A.z * al));
    A.w = fmaf(p1, v1.w, fmaf(p0, v0.w, A.w * al));
}
__device__ inline void merge4(float4& A, const float4 B, float c1, float c2) {
    A.x = A.x * c1 + B.x * c2;
    A.y = A.y * c1 + B.y * c2;
    A.z = A.z * c1 + B.z * c2;
    A.w = A.w * c1 + B.w * c2;
}
__device__ inline float4 shfl4(const float4 a, int off) {
    float4 r;
    r.x = __shfl_xor(a.x, off, 64); r.y = __shfl_xor(a.y, off, 64);
    r.z = __shfl_xor(a.z, off, 64); r.w = __shfl_xor(a.w, off, 64);
    return r;
}

// ---------------------------------------------------------------------------
// Tiled cross attention (r8-proven, unchanged): Q_LOCAL=4, double-buffered
// LDS, base-2 softmax via raw v_exp_f32, CH_MOL=4 / CH_PROT=2.
__global__ __launch_bounds__(256) void k_attn(
    const float* __restrict__ Qm, const float* __restrict__ Kp, const float* __restrict__ Vp,
    const float* __restrict__ Qp, const float* __restrict__ Km, const float* __restrict__ Vm,
    float* __restrict__ part_m, float* __restrict__ part_p) {
    __shared__ float Kl[2][TKA * KSTA];
    __shared__ float Vl[2][TKA * KSTA];

    int t = threadIdx.x;
    const float *Q, *K, *V;
    float* part;
    int q0, chunk, CH;
    {
        int b = blockIdx.x;
        const int MOLB = NGRP_MOL * CH_MOL;   // 512
        if (b < MOLB) {
            chunk = b & 3; q0 = (b >> 2) * TQA; CH = CH_MOL;
            Q = Qm; K = Kp; V = Vp; part = part_m;
        } else {
            b -= MOLB;
            chunk = b & 1; q0 = (b >> 1) * TQA; CH = CH_PROT;
            Q = Qp; K = Km; V = Vm; part = part_p;
        }
    }
    int kbeg = chunk * KCHUNK;

    int sub = t & 15, h = (t >> 4) & 3, qg = t >> 6;
    int r0 = t >> 4;                 // staging row 0..15 (and r0+16)
    int c0 = (t & 15) << 2;          // staging col (words)

    const float sc = 0.25f * 1.44269504088896f;   // 1/sqrt(16) * log2(e)
    float4 q4[4][4];
#pragma unroll
    for (int qq = 0; qq < 4; ++qq) {
        const float4* Qr = (const float4*)(Q + (q0 + qg * 4 + qq) * HID + h * HDIM);
#pragma unroll
        for (int j = 0; j < 4; ++j) {
            float4 v = Qr[j];
            v.x *= sc; v.y *= sc; v.z *= sc; v.w *= sc;
            q4[qq][j] = v;
        }
    }

    float mreg[4], lreg[4];
    float4 A[4][4];
#pragma unroll
    for (int qq = 0; qq < 4; ++qq) {
        mreg[qq] = -INFINITY; lreg[qq] = 0.f;
#pragma unroll
        for (int j = 0; j < 4; ++j) A[qq][j] = (float4){0.f, 0.f, 0.f, 0.f};
    }

    // prologue: stage tile 0 into buffer 0
    {
        const float4* Kg = (const float4*)(K + kbeg * HID);
        const float4* Vg = (const float4*)(V + kbeg * HID);
        float4 ka = Kg[t], kb = Kg[t + 256];
        float4 va = Vg[t], vb = Vg[t + 256];
        *(float4*)&Kl[0][r0 * KSTA + c0] = ka;
        *(float4*)&Kl[0][(r0 + 16) * KSTA + c0] = kb;
        *(float4*)&Vl[0][r0 * KSTA + c0] = va;
        *(float4*)&Vl[0][(r0 + 16) * KSTA + c0] = vb;
    }
    __syncthreads();

    const int NT = KCHUNK / TKA;     // 32 tiles
    for (int tile = 0; tile < NT; ++tile) {
        int cur = tile & 1;
        float4 ka, kb, va, vb;
        bool more = (tile + 1) < NT;
        if (more) {
            const float4* Kg = (const float4*)(K + (kbeg + (tile + 1) * TKA) * HID);
            const float4* Vg = (const float4*)(V + (kbeg + (tile + 1) * TKA) * HID);
            ka = Kg[t]; kb = Kg[t + 256];
            va = Vg[t]; vb = Vg[t + 256];
        }

        const float4* Kr0 = (const float4*)&Kl[cur][sub * KSTA + h * HDIM];
        const float4* Kr1 = (const float4*)&Kl[cur][(sub + 16) * KSTA + h * HDIM];
        float4 x0 = Kr0[0], x1 = Kr0[1], x2 = Kr0[2], x3 = Kr0[3];
        float4 y0 = Kr1[0], y1 = Kr1[1], y2 = Kr1[2], y3 = Kr1[3];

        float s0[4], s1[4];
#pragma unroll
        for (int qq = 0; qq < 4; ++qq) {
            s0[qq] = DOT4(x0, q4[qq][0]) + DOT4(x1, q4[qq][1]) + DOT4(x2, q4[qq][2]) + DOT4(x3, q4[qq][3]);
            s1[qq] = DOT4(y0, q4[qq][0]) + DOT4(y1, q4[qq][1]) + DOT4(y2, q4[qq][2]) + DOT4(y3, q4[qq][3]);
        }

        const float4* Vr0 = (const float4*)&Vl[cur][sub * KSTA + h * HDIM];
        const float4* Vr1 = (const float4*)&Vl[cur][(sub + 16) * KSTA + h * HDIM];
        float4 v00 = Vr0[0], v01 = Vr0[1], v02 = Vr0[2], v03 = Vr0[3];
        float4 v10 = Vr1[0], v11 = Vr1[1], v12 = Vr1[2], v13 = Vr1[3];

#pragma unroll
        for (int qq = 0; qq < 4; ++qq) {
            float mn = fmaxf(mreg[qq], fmaxf(s0[qq], s1[qq]));
            float al = EXP2(mreg[qq] - mn);
            float p0 = EXP2(s0[qq] - mn);
            float p1 = EXP2(s1[qq] - mn);
            lreg[qq] = lreg[qq] * al + p0 + p1;
            upd4(A[qq][0], v00, v10, p0, p1, al);
            upd4(A[qq][1], v01, v11, p0, p1, al);
            upd4(A[qq][2], v02, v12, p0, p1, al);
            upd4(A[qq][3], v03, v13, p0, p1, al);
            mreg[qq] = mn;
        }

        if (more) {
            int nxt = cur ^ 1;
            *(float4*)&Kl[nxt][r0 * KSTA + c0] = ka;
            *(float4*)&Kl[nxt][(r0 + 16) * KSTA + c0] = kb;
            *(float4*)&Vl[nxt][r0 * KSTA + c0] = va;
            *(float4*)&Vl[nxt][(r0 + 16) * KSTA + c0] = vb;
        }
        __syncthreads();
    }

    // merge 16 partial states across sub lanes (lane bits 0..3)
#pragma unroll
    for (int off = 1; off < 16; off <<= 1) {
#pragma unroll
        for (int qq = 0; qq < 4; ++qq) {
            float m2 = __shfl_xor(mreg[qq], off, 64);
            float l2 = __shfl_xor(lreg[qq], off, 64);
            float4 B0 = shfl4(A[qq][0], off), B1 = shfl4(A[qq][1], off);
            float4 B2 = shfl4(A[qq][2], off), B3 = shfl4(A[qq][3], off);
            float mn = fmaxf(mreg[qq], m2);
            float c1 = EXP2(mreg[qq] - mn), c2 = EXP2(m2 - mn);
            lreg[qq] = lreg[qq] * c1 + l2 * c2;
            merge4(A[qq][0], B0, c1, c2); merge4(A[qq][1], B1, c1, c2);
            merge4(A[qq][2], B2, c1, c2); merge4(A[qq][3], B3, c1, c2);
            mreg[qq] = mn;
        }
    }

    if (sub == 0) {
#pragma unroll
        for (int qq = 0; qq < 4; ++qq) {
            int qi = q0 + qg * 4 + qq;
            float* pp = part + (size_t)((qi * HEADS + h) * CH + chunk) * 20;
            pp[0] = mreg[qq]; pp[1] = lreg[qq];
            *(float4*)&pp[4] = A[qq][0]; *(float4*)&pp[8] = A[qq][1];
            *(float4*)&pp[12] = A[qq][2]; *(float4*)&pp[16] = A[qq][3];
        }
    }
}

// ---------------------------------------------------------------------------
// Parallel chunk-merge + residual + pool. Grid = BATCH*8: batch b=blk>>3,
// node-slice sl=blk&7. Partial sums -> LDS reduce -> 128 atomicAdds to pool.
// Slice 0 writes counts (single writer). All 256 CUs active.
__global__ void k_pool(const float* __restrict__ part_m, const float* __restrict__ part_p,
                       const float* __restrict__ xm, const float* __restrict__ xp,
                       const int* __restrict__ mb, const int* __restrict__ pb,
                       float* __restrict__ pool, float* __restrict__ cnt) {
    __shared__ float sm[64][65];
    int b = blockIdx.x >> 3, sl = blockIdx.x & 7;
    int t = threadIdx.x;
    int h = t & 3, s = t >> 2;
    int ms, me, ps, pe;
    {
        int lo = 0, hi = N_MOL;
        while (lo < hi) { int mid = (lo + hi) >> 1; if (mb[mid] < b) lo = mid + 1; else hi = mid; }
        ms = lo; lo = ms; hi = N_MOL;
        while (lo < hi) { int mid = (lo + hi) >> 1; if (mb[mid] < b + 1) lo = mid + 1; else hi = mid; }
        me = lo;
        lo = 0; hi = N_PROT;
        while (lo < hi) { int mid = (lo + hi) >> 1; if (pb[mid] < b) lo = mid + 1; else hi = mid; }
        ps = lo; lo = ps; hi = N_PROT;
        while (lo < hi) { int mid = (lo + hi) >> 1; if (pb[mid] < b + 1) lo = mid + 1; else hi = mid; }
        pe = lo;
    }
    if (sl == 0 && t == 0) { cnt[b * 2] = (float)(me - ms); cnt[b * 2 + 1] = (float)(pe - ps); }

    // ---- mol (CH_MOL chunks): nodes q with (q-ms) % 8 == sl, slot-strided
    {
        float acc[16];
#pragma unroll
        for (int d = 0; d < 16; ++d) acc[d] = 0.f;
        for (int q = ms + sl + 8 * s; q < me; q += 8 * 64) {
            const float* p0 = part_m + (size_t)(q * HEADS + h) * CH_MOL * 20;
            float mmax = -INFINITY;
#pragma unroll
            for (int c = 0; c < CH_MOL; ++c) mmax = fmaxf(mmax, p0[c * 20]);
            float lsum = 0.f, wgt[CH_MOL];
#pragma unroll
            for (int c = 0; c < CH_MOL; ++c) {
                wgt[c] = EXP2(p0[c * 20] - mmax);
                lsum += p0[c * 20 + 1] * wgt[c];
            }
            float inv = 1.f / lsum;
            const float* Xr = xm + q * HID + h * HDIM;
#pragma unroll
            for (int d = 0; d < 16; ++d) {
                float o = Xr[d];
#pragma unroll
                for (int c = 0; c < CH_MOL; ++c)
                    o = fmaf(p0[c * 20 + 4 + d], wgt[c] * inv, o);
                acc[d] += o;
            }
        }
#pragma unroll
        for (int d = 0; d < 16; ++d) sm[s][h * 16 + d] = acc[d];
    }
    __syncthreads();
    if (t < 64) {
        float sum = 0.f;
        for (int ss = 0; ss < 64; ++ss) sum += sm[ss][t];
        unsafeAtomicAdd(&pool[b * 128 + t], sum);
    }
    __syncthreads();

    // ---- prot (CH_PROT chunks)
    {
        float acc[16];
#pragma unroll
        for (int d = 0; d < 16; ++d) acc[d] = 0.f;
        for (int q = ps + sl + 8 * s; q < pe; q += 8 * 64) {
            const float* p0 = part_p + (size_t)(q * HEADS + h) * CH_PROT * 20;
            float m0 = p0[0], m1 = p0[20];
            float mmax = fmaxf(m0, m1);
            float w0 = EXP2(m0 - mmax), w1 = EXP2(m1 - mmax);
            float inv = 1.f / (p0[1] * w0 + p0[21] * w1);
            w0 *= inv; w1 *= inv;
            const float* Xr = xp + q * HID + h * HDIM;
#pragma unroll
            for (int d = 0; d < 16; ++d)
                acc[d] += Xr[d] + p0[4 + d] * w0 + p0[24 + d] * w1;
        }
#pragma unroll
        for (int d = 0; d < 16; ++d) sm[s][h * 16 + d] = acc[d];
    }
    __syncthreads();
    if (t < 64) {
        float sum = 0.f;
        for (int ss = 0; ss < 64; ++ss) sum += sm[ss][t];
        unsafeAtomicAdd(&pool[b * 128 + 64 + t], sum);
    }
}

// ---------------------------------------------------------------------------
// Head: z = pool/cnt; relu(z@fc1+b1)@fc2+b2 -> sigmoid. 32 blocks x 64.
__global__ void k_head(const float* __restrict__ pool, const float* __restrict__ cnt,
                       const float* __restrict__ fc1W, const float* __restrict__ fc1b,
                       const float* __restrict__ fc2W, const float* __restrict__ fc2b,
                       float* __restrict__ out) {
    __shared__ float z[128];
    int b = blockIdx.x, t = threadIdx.x;
    float cm = fmaxf(cnt[b * 2 + 0], 1.f), cp = fmaxf(cnt[b * 2 + 1], 1.f);
    z[t] = pool[b * 128 + t] / cm;
    z[64 + t] = pool[b * 128 + 64 + t] / cp;
    __syncthreads();
    float acc = fc1b[t];
    const float4* zv = (const float4*)z;
#pragma unroll
    for (int k = 0; k < 32; ++k) {
        float4 hv = zv[k];
        acc = fmaf(hv.x, fc1W[(4 * k + 0) * 64 + t], acc);
        acc = fmaf(hv.y, fc1W[(4 * k + 1) * 64 + t], acc);
        acc = fmaf(hv.z, fc1W[(4 * k + 2) * 64 + t], acc);
        acc = fmaf(hv.w, fc1W[(4 * k + 3) * 64 + t], acc);
    }
    float hv = fmaxf(acc, 0.f);
    float prod = hv * fc2W[t];
#pragma unroll
    for (int off = 32; off > 0; off >>= 1) prod += __shfl_xor(prod, off, 64);
    if (t == 0) out[b] = 1.f / (1.f + __expf(-(prod + fc2b[0])));
}

// ---------------------------------------------------------------------------
extern "C" void kernel_launch(void* const* d_in, const int* in_sizes, int n_in,
                              void* d_out, int out_size, void* d_ws, size_t ws_size,
                              hipStream_t stream) {
    const float* mol_x   = (const float*)d_in[0];
    const float* prot_x  = (const float*)d_in[1];
    const float* mol_ea  = (const float*)d_in[2];
    const float* prot_ea = (const float*)d_in[3];
    const int*   mol_ei  = (const int*)d_in[4];
    const int*   prot_ei = (const int*)d_in[5];
    const int*   mol_b   = (const int*)d_in[6];
    const int*   prot_b  = (const int*)d_in[7];
    const float* nlmW = (const float*)d_in[8];
    const float* nlmb = (const float*)d_in[9];
    const float* nlpW = (const float*)d_in[10];
    const float* nlpb = (const float*)d_in[11];
    const float* elmW = (const float*)d_in[12];
    const float* elmb = (const float*)d_in[13];
    const float* elpW = (const float*)d_in[14];
    const float* elpb = (const float*)d_in[15];
    const float* mcW1 = (const float*)d_in[16];
    const float* mcb1 = (const float*)d_in[17];
    const float* mcW2 = (const float*)d_in[18];
    const float* mcb2 = (const float*)d_in[19];
    const float* pcW1 = (const float*)d_in[20];
    const float* pcb1 = (const float*)d_in[21];
    const float* pcW2 = (const float*)d_in[22];
    const float* pcb2 = (const float*)d_in[23];
    const float* mpW  = (const float*)d_in[24];
    const float* mpb  = (const float*)d_in[25];
    const float* pmW  = (const float*)d_in[26];
    const float* pmb  = (const float*)d_in[27];
    const float* fc1W = (const float*)d_in[28];
    const float* fc1b = (const float*)d_in[29];
    const float* fc2W = (const float*)d_in[30];
    const float* fc2b = (const float*)d_in[31];

    float* ws    = (float*)d_ws;
    float* xa_m  = ws;                  // 131072
    float* xa_p  = xa_m + 131072;       // 262144
    float* xb_m  = xa_p + 262144;       // 131072
    float* xb_p  = xb_m + 131072;       // 262144
    float* Qm    = xb_p + 262144;       // 131072
    float* Kp    = Qm + 131072;         // 262144
    float* Vp    = Kp + 262144;         // 262144
    float* Qp    = Vp + 262144;         // 262144
    float* Km    = Qp + 262144;         // 131072
    float* Vm    = Km + 131072;         // 131072
    float* partm = Vm + 131072;         // 2048*4*4*20 = 655360
    float* partp = partm + 655360;      // 4096*4*2*20 = 655360
    int* cursor  = (int*)(partp + 655360);  // 6144 ints } one contiguous
    float* pool  = (float*)(cursor + N_TOT); // 4096     } memset
    float* cnt   = pool + 4096;              // 64       }
    // eidx aliases partm: used only before k_attn (3.1 MB < 5.2 MB)
    int* eidx    = (int*)partm;

    hipMemsetAsync(cursor, 0, (size_t)(N_TOT + 4096 + 64) * 4, stream);

    k_nlb<<<N_TOT / 4 + E_TOT / 256, 256, 0, stream>>>(
        mol_x, prot_x, nlmW, nlmb, nlpW, nlpb, mol_ei, prot_ei, xa_m, xa_p, cursor, eidx);

    k_gine<<<N_TOT / 8, 256, 0, stream>>>(xa_m, xa_p, xb_m, xb_p, mol_ea, prot_ea, mol_ei, prot_ei,
        elmW, elmb, elpW, elpb,
        mcW1, mcb1, mcW2, mcb2, pcW1, pcb1, pcW2, pcb2, cursor, eidx,
        0, mpW, mpb, pmW, pmb, Qm, Kp, Vp, Qp, Km, Vm);
    k_gine<<<N_TOT / 8, 256, 0, stream>>>(xb_m, xb_p, xa_m, xa_p, mol_ea, prot_ea, mol_ei, prot_ei,
        elmW, elmb, elpW, elpb,
        mcW1 + 4096, mcb1 + 64, mcW2 + 4096, mcb2 + 64,
        pcW1 + 4096, pcb1 + 64, pcW2 + 4096, pcb2 + 64, cursor, eidx,
        0, mpW, mpb, pmW, pmb, Qm, Kp, Vp, Qp, Km, Vm);
    k_gine<<<N_TOT / 8, 256, 0, stream>>>(xa_m, xa_p, xb_m, xb_p, mol_ea, prot_ea, mol_ei, prot_ei,
        elmW, elmb, elpW, elpb,
        mcW1 + 8192, mcb1 + 128, mcW2 + 8192, mcb2 + 128,
        pcW1 + 8192, pcb1 + 128, pcW2 + 8192, pcb2 + 128, cursor, eidx,
        1, mpW, mpb, pmW, pmb, Qm, Kp, Vp, Qp, Km, Vm);

    k_attn<<<NGRP_MOL * CH_MOL + (N_PROT / TQA) * CH_PROT, 256, 0, stream>>>(
        Qm, Kp, Vp, Qp, Km, Vm, partm, partp);

    k_pool<<<BATCH * 8, 256, 0, stream>>>(partm, partp, xb_m, xb_p, mol_b, prot_b, pool, cnt);
    k_head<<<BATCH, 64, 0, stream>>>(pool, cnt, fc1W, fc1b, fc2W, fc2b, (float*)d_out);
}